// Round 5
// baseline (95.778 us; speedup 1.0000x reference)
//
#include <hip/hip_runtime.h>

// GaussianBlur 3x3 sigma=0 -> separable [0.25,0.5,0.25], BORDER_REFLECT_101.
// f32 [64,3,512,512]. One wave (64 lanes x 8 px) covers one full 512-px row.
// Each thread produces 8 px in each of 8 consecutive rows (10 input rows
// loaded, 20 b128 loads -> deep MLP). Horizontal neighbors via lane
// shuffles; nontemporal stores keep the input L3-resident across replays.

#define HH 512
#define WW 512

// native clang ext-vector: accepted by __builtin_nontemporal_store
typedef float f4 __attribute__((ext_vector_type(4)));

#define VBLUR(d, m, c, pq)                         \
    d.x = 0.25f * (m.x + pq.x) + 0.5f * c.x;       \
    d.y = 0.25f * (m.y + pq.y) + 0.5f * c.y;       \
    d.z = 0.25f * (m.z + pq.z) + 0.5f * c.z;       \
    d.w = 0.25f * (m.w + pq.w) + 0.5f * c.w;

#define HBLUR(oa, ob, ua, ub, l, r)                \
    oa.x = 0.25f * (l    + ua.y) + 0.5f * ua.x;    \
    oa.y = 0.25f * (ua.x + ua.z) + 0.5f * ua.y;    \
    oa.z = 0.25f * (ua.y + ua.w) + 0.5f * ua.z;    \
    oa.w = 0.25f * (ua.z + ub.x) + 0.5f * ua.w;    \
    ob.x = 0.25f * (ua.w + ub.y) + 0.5f * ub.x;    \
    ob.y = 0.25f * (ub.x + ub.z) + 0.5f * ub.y;    \
    ob.z = 0.25f * (ub.y + ub.w) + 0.5f * ub.z;    \
    ob.w = 0.25f * (ub.z + r   ) + 0.5f * ub.w;

// vertical blur of (ma,mb|ca,cb|pa,pb), then shuffle edges, horizontal blur,
// NT store of one output row
#define ROW(ma, mb, ca, cb, pa, pb, h)                               \
    {                                                                \
        f4 ua, ub;                                                   \
        VBLUR(ua, ma, ca, pa)                                        \
        VBLUR(ub, mb, cb, pb)                                        \
        float l = __shfl_up(ub.w, 1);                                \
        float r = __shfl_down(ua.x, 1);                              \
        if (lane == 0)  l = ua.y;                                    \
        if (lane == 63) r = ub.z;                                    \
        f4 oa, ob;                                                   \
        HBLUR(oa, ob, ua, ub, l, r)                                  \
        f4* S = (f4*)(q + (size_t)(h) * WW + w0);                    \
        __builtin_nontemporal_store(oa, S);                          \
        __builtin_nontemporal_store(ob, S + 1);                      \
    }

__global__ __launch_bounds__(256) void gauss3_kernel(const float* __restrict__ in,
                                                     float* __restrict__ out) {
    int wid  = (blockIdx.x * 256 + threadIdx.x) >> 6;  // global wave id
    int lane = threadIdx.x & 63;

    int oct   = wid & 63;    // 64 row-octets per (b,c) plane
    int plane = wid >> 6;

    int h0 = oct << 3;                            // output rows h0 .. h0+7
    int hm = (h0 == 0)       ? 1      : h0 - 1;   // reflect-101
    int hp = (h0 + 8 == HH)  ? HH - 2 : h0 + 8;   // reflect-101

    const float* p = in  + (size_t)plane * (HH * WW);
    float*       q = out + (size_t)plane * (HH * WW);
    int w0 = lane << 3;  // 8 px per lane

    const float* base = p + w0;

    // 20 wide loads (10 rows x 2 f4) -- deep MLP
    const f4* Lm = (const f4*)(base + (size_t)hm * WW);
    const f4* L0 = (const f4*)(base + (size_t)(h0    ) * WW);
    const f4* L1 = (const f4*)(base + (size_t)(h0 + 1) * WW);
    const f4* L2 = (const f4*)(base + (size_t)(h0 + 2) * WW);
    const f4* L3 = (const f4*)(base + (size_t)(h0 + 3) * WW);
    const f4* L4 = (const f4*)(base + (size_t)(h0 + 4) * WW);
    const f4* L5 = (const f4*)(base + (size_t)(h0 + 5) * WW);
    const f4* L6 = (const f4*)(base + (size_t)(h0 + 6) * WW);
    const f4* L7 = (const f4*)(base + (size_t)(h0 + 7) * WW);
    const f4* Lp = (const f4*)(base + (size_t)hp * WW);

    f4 ma  = Lm[0], mb  = Lm[1];
    f4 r0a = L0[0], r0b = L0[1];
    f4 r1a = L1[0], r1b = L1[1];
    f4 r2a = L2[0], r2b = L2[1];
    f4 r3a = L3[0], r3b = L3[1];
    f4 r4a = L4[0], r4b = L4[1];
    f4 r5a = L5[0], r5b = L5[1];
    f4 r6a = L6[0], r6b = L6[1];
    f4 r7a = L7[0], r7b = L7[1];
    f4 pa  = Lp[0], pb  = Lp[1];

    ROW(ma,  mb,  r0a, r0b, r1a, r1b, h0)
    ROW(r0a, r0b, r1a, r1b, r2a, r2b, h0 + 1)
    ROW(r1a, r1b, r2a, r2b, r3a, r3b, h0 + 2)
    ROW(r2a, r2b, r3a, r3b, r4a, r4b, h0 + 3)
    ROW(r3a, r3b, r4a, r4b, r5a, r5b, h0 + 4)
    ROW(r4a, r4b, r5a, r5b, r6a, r6b, h0 + 5)
    ROW(r5a, r5b, r6a, r6b, r7a, r7b, h0 + 6)
    ROW(r6a, r6b, r7a, r7b, pa,  pb,  h0 + 7)
}

extern "C" void kernel_launch(void* const* d_in, const int* in_sizes, int n_in,
                              void* d_out, int out_size, void* d_ws, size_t ws_size,
                              hipStream_t stream) {
    const float* x   = (const float*)d_in[0];
    float*       out = (float*)d_out;

    int n      = in_sizes[0];          // 64*3*512*512
    int planes = n / (HH * WW);        // 192
    int waves  = planes * (HH / 8);    // one wave per row-octet: 12288
    int blocks = waves / 4;            // 4 waves per 256-thread block: 3072

    gauss3_kernel<<<blocks, 256, 0, stream>>>(x, out);
}

// Round 6
// 76.315 us; speedup vs baseline: 1.2550x; 1.2550x over previous
//
#include <hip/hip_runtime.h>

// GaussianBlur 3x3 sigma=0 -> separable [0.25,0.5,0.25], BORDER_REFLECT_101.
// f32 [64,3,512,512]. One wave (64 lanes x 8 px) covers one full 512-px row.
// Each thread produces 8 px in each of 4 consecutive rows (6 input rows, 12
// b128 loads hoisted up front). __launch_bounds__(256,4) gives the register
// allocator headroom (~128 VGPR) so the loads actually stay hoisted -- at the
// default occupancy target the compiler capped VGPR at 32 and serialized
// them (R5 regression). Horizontal neighbors via lane shuffles; nontemporal
// stores keep the input L3-resident (FETCH 196->110 MB measured).

#define HH 512
#define WW 512

// native clang ext-vector: accepted by __builtin_nontemporal_store
typedef float f4 __attribute__((ext_vector_type(4)));

#define VBLUR(d, m, c, pq)                         \
    d.x = 0.25f * (m.x + pq.x) + 0.5f * c.x;       \
    d.y = 0.25f * (m.y + pq.y) + 0.5f * c.y;       \
    d.z = 0.25f * (m.z + pq.z) + 0.5f * c.z;       \
    d.w = 0.25f * (m.w + pq.w) + 0.5f * c.w;

#define HBLUR(oa, ob, ua, ub, l, r)                \
    oa.x = 0.25f * (l    + ua.y) + 0.5f * ua.x;    \
    oa.y = 0.25f * (ua.x + ua.z) + 0.5f * ua.y;    \
    oa.z = 0.25f * (ua.y + ua.w) + 0.5f * ua.z;    \
    oa.w = 0.25f * (ua.z + ub.x) + 0.5f * ua.w;    \
    ob.x = 0.25f * (ua.w + ub.y) + 0.5f * ub.x;    \
    ob.y = 0.25f * (ub.x + ub.z) + 0.5f * ub.y;    \
    ob.z = 0.25f * (ub.y + ub.w) + 0.5f * ub.z;    \
    ob.w = 0.25f * (ub.z + r   ) + 0.5f * ub.w;

// per-row: shuffle edges, reflect at lane 0/63, horizontal blur, NT store
#define ROW_FINISH(ua, ub, h)                                        \
    {                                                                \
        float l = __shfl_up(ub.w, 1);                                \
        float r = __shfl_down(ua.x, 1);                              \
        if (lane == 0)  l = ua.y;                                    \
        if (lane == 63) r = ub.z;                                    \
        f4 oa, ob;                                                   \
        HBLUR(oa, ob, ua, ub, l, r)                                  \
        f4* S = (f4*)(q + (size_t)(h) * WW + w0);                    \
        __builtin_nontemporal_store(oa, S);                          \
        __builtin_nontemporal_store(ob, S + 1);                      \
    }

__global__ __launch_bounds__(256, 4) void gauss3_kernel(const float* __restrict__ in,
                                                        float* __restrict__ out) {
    int wid  = (blockIdx.x * 256 + threadIdx.x) >> 6;  // global wave id
    int lane = threadIdx.x & 63;

    int quad  = wid & 127;   // 128 row-quads per (b,c) plane
    int plane = wid >> 7;

    int h0 = quad << 2;                           // output rows h0 .. h0+3
    int hm = (h0 == 0)       ? 1      : h0 - 1;   // reflect-101
    int hp = (h0 + 4 == HH)  ? HH - 2 : h0 + 4;   // reflect-101

    const float* p = in  + (size_t)plane * (HH * WW);
    float*       q = out + (size_t)plane * (HH * WW);
    int w0 = lane << 3;  // 8 px per lane

    const f4* Lm = (const f4*)(p + (size_t)hm       * WW + w0);
    const f4* L0 = (const f4*)(p + (size_t)h0       * WW + w0);
    const f4* L1 = (const f4*)(p + (size_t)(h0 + 1) * WW + w0);
    const f4* L2 = (const f4*)(p + (size_t)(h0 + 2) * WW + w0);
    const f4* L3 = (const f4*)(p + (size_t)(h0 + 3) * WW + w0);
    const f4* Lp = (const f4*)(p + (size_t)hp       * WW + w0);

    // 12 wide loads up front (MLP) -- VGPR headroom keeps these hoisted
    f4 ama = Lm[0], amb = Lm[1];
    f4 a0a = L0[0], a0b = L0[1];
    f4 a1a = L1[0], a1b = L1[1];
    f4 a2a = L2[0], a2b = L2[1];
    f4 a3a = L3[0], a3b = L3[1];
    f4 apa = Lp[0], apb = Lp[1];

    // vertical blur per output row, then finish + store
    f4 ua, ub;
    VBLUR(ua, ama, a0a, a1a)  VBLUR(ub, amb, a0b, a1b)
    ROW_FINISH(ua, ub, h0)
    VBLUR(ua, a0a, a1a, a2a)  VBLUR(ub, a0b, a1b, a2b)
    ROW_FINISH(ua, ub, h0 + 1)
    VBLUR(ua, a1a, a2a, a3a)  VBLUR(ub, a1b, a2b, a3b)
    ROW_FINISH(ua, ub, h0 + 2)
    VBLUR(ua, a2a, a3a, apa)  VBLUR(ub, a2b, a3b, apb)
    ROW_FINISH(ua, ub, h0 + 3)
}

extern "C" void kernel_launch(void* const* d_in, const int* in_sizes, int n_in,
                              void* d_out, int out_size, void* d_ws, size_t ws_size,
                              hipStream_t stream) {
    const float* x   = (const float*)d_in[0];
    float*       out = (float*)d_out;

    int n      = in_sizes[0];          // 64*3*512*512
    int planes = n / (HH * WW);        // 192
    int waves  = planes * (HH / 4);    // one wave per row-quad: 24576
    int blocks = waves / 4;            // 4 waves per 256-thread block: 6144

    gauss3_kernel<<<blocks, 256, 0, stream>>>(x, out);
}